// Round 10
// baseline (104.236 us; speedup 1.0000x reference)
//
#include <hip/hip_runtime.h>
#include <hip/hip_bf16.h>
#include <hip/hip_fp16.h>

typedef __attribute__((ext_vector_type(8))) short short8;   // 8 x bf16 (4 VGPRs)
typedef __attribute__((ext_vector_type(4))) float f32x4;    // MFMA accumulator

#define OUT_F  11008
#define IN_F   4096
#define BN     64
#define SPLITS 4
#define KSTEPS 8              // 128-wide K steps per split (4*8*128 = 4096)
#define NB     (OUT_F / BN)   // 172
#define WB     8192           // one RAW W buffer: 64 rows x 128 B
#define AB     8192           // one A buffer: 32 rows x 128 bf16 (swizzled)

// ---------- helpers ----------
static __device__ __forceinline__ uint pack2_bf16(float a, float b) {
    __hip_bfloat162 h = __float22bfloat162_rn(make_float2(a, b));
    uint u;
    __builtin_memcpy(&u, &h, 4);
    return u;
}

static __device__ __forceinline__ float bf16_to_f(ushort u) {
    return __uint_as_float(((uint)u) << 16);
}

// dequant 8 weights (2 packed ints, low bytes) -> short8 bf16
static __device__ __forceinline__ short8 dq8(int2 p, float xmin, float dd) {
    uint u0 = pack2_bf16(fmaf((float)(p.x & 3), dd, xmin),
                         fmaf((float)((p.x >> 2) & 3), dd, xmin));
    uint u1 = pack2_bf16(fmaf((float)((p.x >> 4) & 3), dd, xmin),
                         fmaf((float)((p.x >> 6) & 3), dd, xmin));
    uint u2 = pack2_bf16(fmaf((float)(p.y & 3), dd, xmin),
                         fmaf((float)((p.y >> 2) & 3), dd, xmin));
    uint u3 = pack2_bf16(fmaf((float)((p.y >> 4) & 3), dd, xmin),
                         fmaf((float)((p.y >> 6) & 3), dd, xmin));
    uint4 q = make_uint4(u0, u1, u2, u3);
    short8 r;
    __builtin_memcpy(&r, &q, 16);
    return r;
}

static __device__ __forceinline__ void rng_decode(uint ru, float2 rf, int fmt,
                                                  float& xmin, float& dd) {
    float xmax;
    if (fmt == 2) {
        xmin = rf.x; xmax = rf.y;
    } else if (fmt == 1) {
        xmin = bf16_to_f((ushort)(ru & 0xffff));
        xmax = bf16_to_f((ushort)(ru >> 16));
    } else {
        __half2 h;
        __builtin_memcpy(&h, &ru, 4);
        xmin = __half2float(h.x); xmax = __half2float(h.y);
    }
    dd = (xmax - xmin) * (1.0f / 3.0f);
}

static __device__ __forceinline__ void gload16(const void* g, void* l) {
    __builtin_amdgcn_global_load_lds((const __attribute__((address_space(1))) void*)g,
                                     (__attribute__((address_space(3))) void*)l,
                                     16, 0, 0);
}

// ---------- kernel 1: fused detect + raw-stage + dequant-on-read GEMM ----------
__global__ __launch_bounds__(256, 3)
void gemm_kernel(const float* __restrict__ x,
                 const int* __restrict__ packed,
                 const void* __restrict__ rr,
                 float* __restrict__ part) {
    const int nb   = blockIdx.x;   // 0..171 (64 output cols)
    const int s    = blockIdx.y;   // 0..3   (K split: 1024 each)
    const int t    = threadIdx.x;
    const int lane = t & 63;
    const int wv   = t >> 6;

    __shared__ __align__(16) char lds[3 * WB + 2 * AB];   // 40 KiB
    __shared__ int s_viol[3];
    __shared__ int s_max[3];
    __shared__ int s_fmt;

    // ---- block-local range-dtype detection (verbatim from passing rounds) ----
    if (t < 3) { s_viol[t] = 0; s_max[t] = 0; }
    __syncthreads();
    {
        const int g = 1024 + t;   // f32-view reads bytes [8192,10240): in-bounds for all fmts
        const uint   ru = ((const uint*)rr)[g];
        const float2 rf = ((const float2*)rr)[g];
        int viol[3]; float mx[3];
        {   // h0: fp16 pairs
            __half2 h; __builtin_memcpy(&h, &ru, 4);
            const float a = __half2float(h.x), c = __half2float(h.y);
            viol[0] = !(fabsf(a) < 1.f && fabsf(c) < 1.f && a <= c);
            mx[0] = fabsf(c);
        }
        {   // h1: bf16 pairs
            const float a = bf16_to_f((ushort)(ru & 0xffff));
            const float c = bf16_to_f((ushort)(ru >> 16));
            viol[1] = !(fabsf(a) < 1.f && fabsf(c) < 1.f && a <= c);
            mx[1] = fabsf(c);
        }
        {   // h2: f32 pairs
            viol[2] = !(fabsf(rf.x) < 1.f && fabsf(rf.y) < 1.f && rf.x <= rf.y);
            mx[2] = fabsf(rf.y);
        }
#pragma unroll
        for (int h = 0; h < 3; ++h) {
            if (viol[h]) atomicOr(&s_viol[h], 1);
            atomicMax(&s_max[h], __float_as_int(mx[h]));
        }
    }
    __syncthreads();
    if (t == 0) {
        const float lo = 0.02f;
        int f = 0;
        if      (!s_viol[2] && __int_as_float(s_max[2]) > lo) f = 2;
        else if (!s_viol[1] && __int_as_float(s_max[1]) > lo) f = 1;
        s_fmt = f;
    }
    __syncthreads();
    const int fmt = s_fmt;   // uniform across block

    // ---- per-block K-step rotation (kept from R9; harmless) ----
    const int rot = (nb * 3 + s) & 7;

    // ---- W staging: lane covers rows {wv*8 + lane>>3, +32}, 16 B each ----
    const int sr0 = wv * 8 + (lane >> 3);
    const int sr1 = sr0 + 32;
    const char* gw0 = (const char*)packed + (size_t)(nb * BN + sr0) * 4096 + s * 1024
                      + (uint)(((lane & 7) * 16) ^ ((sr0 & 7) << 4));
    const char* gw1 = (const char*)packed + (size_t)(nb * BN + sr1) * 4096 + s * 1024
                      + (uint)(((lane & 7) * 16) ^ ((sr1 & 7) << 4));

    // ---- A staging (write): thread covers x row t>>3, 16 f32 at col (t&7)*16 ----
    const float* xsrc = x + (t >> 3) * IN_F + s * 1024 + (t & 7) * 16;
    const uint aswz = (uint)(((t >> 3) & 7) << 4);
    const uint acb  = (uint)((t & 7) * 32);

    // ---- consumers ----
    const int r = lane & 15;           // C col within 16 / A row (acc0)
    const int j = lane >> 4;           // k-slice (k = j*8 .. +8)
    const int nrow = (wv << 4) | r;    // W row this lane dequants
    const int n    = nb * BN + nrow;
    const uint arsw = (uint)((r & 7) << 4);
    const uint rsw  = (uint)((nrow & 7) << 4);
    const int rngidx = n * 32;
    const uint*   rr_u  = (const uint*)rr;
    const float2* rr_f2 = (const float2*)rr;
    const int kb0 = s * KSTEPS;

    char* wbufA = lds;                 // read target (iter i)
    char* wbufB = lds + WB;            // stage target (iter i+1)
    char* wbufC = lds + 2 * WB;
    char* abuf0 = lds + 3 * WB;
    char* abuf1 = abuf0 + AB;

    f32x4 acc0 = {0.f, 0.f, 0.f, 0.f};
    f32x4 acc1 = {0.f, 0.f, 0.f, 0.f};

    // ---- prologue: stage rotated step 0 (gloads FIRST), then its reg loads ----
    {
        const int s0 = rot;
        gload16(gw0 + s0 * 128, wbufA + wv * 1024);
        gload16(gw1 + s0 * 128, wbufA + 4096 + wv * 1024);
    }
    uint  ruc = 0; float2 rfc = {0.f, 0.f};
    if (fmt == 2) rfc = rr_f2[rngidx + kb0 + rot];
    else          ruc = rr_u[rngidx + kb0 + rot];
    float4 xc0, xc1, xc2, xc3;
    {
        const float* xs = xsrc + rot * 128;
        xc0 = *(const float4*)(xs);
        xc1 = *(const float4*)(xs + 4);
        xc2 = *(const float4*)(xs + 8);
        xc3 = *(const float4*)(xs + 12);
    }

#pragma unroll 1
    for (int it = 0; it < KSTEPS; ++it) {
        // (1) stage W(it+1) -> wbufB (wrap-around at it=7: harmless reload)
        const int stn = (it + 1 + rot) & (KSTEPS - 1);
        gload16(gw0 + stn * 128, wbufB + wv * 1024);
        gload16(gw1 + stn * 128, wbufB + 4096 + wv * 1024);

        // (2) reg loads for it+1: ranges + x slice
        uint  run = 0; float2 rfn = {0.f, 0.f};
        if (fmt == 2) rfn = rr_f2[rngidx + kb0 + stn];
        else          run = rr_u[rngidx + kb0 + stn];
        const float* xs = xsrc + stn * 128;
        float4 xn0 = *(const float4*)(xs);
        float4 xn1 = *(const float4*)(xs + 4);
        float4 xn2 = *(const float4*)(xs + 8);
        float4 xn3 = *(const float4*)(xs + 12);

        // (3) pack current x slice -> A tile (bf16, swizzled)
        {
            char* at = (it & 1) ? abuf1 : abuf0;
            uint q0 = pack2_bf16(xc0.x, xc0.y), q1 = pack2_bf16(xc0.z, xc0.w);
            uint q2 = pack2_bf16(xc1.x, xc1.y), q3 = pack2_bf16(xc1.z, xc1.w);
            uint q4 = pack2_bf16(xc2.x, xc2.y), q5 = pack2_bf16(xc2.z, xc2.w);
            uint q6 = pack2_bf16(xc3.x, xc3.y), q7 = pack2_bf16(xc3.z, xc3.w);
            char* adst = at + (t >> 3) * 256;
            *(uint4*)(adst + (acb ^ aswz))        = make_uint4(q0, q1, q2, q3);
            *(uint4*)(adst + ((acb + 16) ^ aswz)) = make_uint4(q4, q5, q6, q7);
        }

        // (4) handoff: drain LDS writes; this iter's 7 VMEM ops stay in flight.
        asm volatile("s_waitcnt lgkmcnt(0) vmcnt(7)" ::: "memory");
        __builtin_amdgcn_s_barrier();
        __builtin_amdgcn_sched_barrier(0);

        // (5) dequant-on-read + MFMA
        {
            const char* at  = (it & 1) ? abuf1 : abuf0;
            const char* as0 = at + r * 256;
            const char* as1 = as0 + 16 * 256;
            const char* wt  = wbufA + nrow * 128;
            float xmin, dd;
            rng_decode(ruc, rfc, fmt, xmin, dd);
#pragma unroll
            for (int kc = 0; kc < 4; ++kc) {
                const uint ao = (uint)((kc << 6) | (j << 4));
                short8 av0 = *(const short8*)(as0 + (ao ^ arsw));
                short8 av1 = *(const short8*)(as1 + (ao ^ arsw));
                const int2 pq = *(const int2*)(wt + ((uint)((kc << 5) | (j << 3)) ^ rsw));
                const short8 bf = dq8(pq, xmin, dd);
                acc0 = __builtin_amdgcn_mfma_f32_16x16x32_bf16(av0, bf, acc0, 0, 0, 0);
                acc1 = __builtin_amdgcn_mfma_f32_16x16x32_bf16(av1, bf, acc1, 0, 0, 0);
            }
        }

        // (6) rotate registers and LDS buffers
        ruc = run; rfc = rfn;
        xc0 = xn0; xc1 = xn1; xc2 = xn2; xc3 = xn3;
        char* tmp = wbufA; wbufA = wbufB; wbufB = wbufC; wbufC = tmp;
    }

    // ---- epilogue: split-K partial stores ----
    // C/D layout col=lane&15, row=(lane>>4)*4+reg (m89-verified)
    float* pout = part + (size_t)s * (32 * OUT_F);
    const int r0 = j << 2;
#pragma unroll
    for (int v = 0; v < 4; ++v) {
        pout[(r0 + v) * OUT_F + n]      = acc0[v];
        pout[(16 + r0 + v) * OUT_F + n] = acc1[v];
    }
}

// ---------- kernel 2: out = bias + sum of split-K partials ----------
__global__ __launch_bounds__(256)
void reduce_kernel(const float* __restrict__ part,
                   const float* __restrict__ bias,
                   float* __restrict__ out) {
    const int i = blockIdx.x * 256 + threadIdx.x;   // 0..88063 float4 units
    const int n4 = i % 2752;                        // 11008/4
    const float4* p4 = (const float4*)part;
    float4 a = ((const float4*)bias)[n4];
#pragma unroll
    for (int ss = 0; ss < SPLITS; ++ss) {
        const float4 v = p4[ss * 88064 + i];
        a.x += v.x; a.y += v.y; a.z += v.z; a.w += v.w;
    }
    ((float4*)out)[i] = a;
}

extern "C" void kernel_launch(void* const* d_in, const int* in_sizes, int n_in,
                              void* d_out, int out_size, void* d_ws, size_t ws_size,
                              hipStream_t stream) {
    const float* x      = (const float*)d_in[0];
    const int*   packed = (const int*)d_in[1];
    const void*  rr     = (const void*)d_in[2];
    const float* bias   = (const float*)d_in[3];
    float*       out    = (float*)d_out;
    float*       part   = (float*)d_ws;   // 4*32*11008 f32 = 5.6 MB

    // ===== ATTRIBUTION EXPERIMENT (deterministic & idempotent) =====
    // gemm writes the same partials every invocation; running it 4x is
    // semantically identical to 1x.  T(this) - T(R9) = 3 * gemm_warm.
    gemm_kernel<<<dim3(NB, SPLITS), 256, 0, stream>>>(x, packed, rr, part);
    gemm_kernel<<<dim3(NB, SPLITS), 256, 0, stream>>>(x, packed, rr, part);
    gemm_kernel<<<dim3(NB, SPLITS), 256, 0, stream>>>(x, packed, rr, part);
    gemm_kernel<<<dim3(NB, SPLITS), 256, 0, stream>>>(x, packed, rr, part);
    reduce_kernel<<<344, 256, 0, stream>>>(part, bias, out);
}

// Round 11
// 63.883 us; speedup vs baseline: 1.6317x; 1.6317x over previous
//
#include <hip/hip_runtime.h>
#include <hip/hip_bf16.h>
#include <hip/hip_fp16.h>

typedef __attribute__((ext_vector_type(8))) short short8;   // 8 x bf16 (4 VGPRs)
typedef __attribute__((ext_vector_type(4))) float f32x4;    // MFMA accumulator

#define OUT_F  11008
#define IN_F   4096
#define BN     64
#define SPLITS 4
#define NB     (OUT_F / BN)     // 172
#define NTILES (NB * SPLITS)    // 688
#define GRID   512              // 2 blocks/CU exactly; persistent grid-stride

// ---------- helpers ----------
static __device__ __forceinline__ uint pack2_bf16(float a, float b) {
    __hip_bfloat162 h = __float22bfloat162_rn(make_float2(a, b));
    uint u;
    __builtin_memcpy(&u, &h, 4);
    return u;
}

static __device__ __forceinline__ float bf16_to_f(ushort u) {
    return __uint_as_float(((uint)u) << 16);
}

// dequant 8 weights (2 packed ints, low bytes) -> short8 bf16  [proven]
static __device__ __forceinline__ short8 dq8(int2 p, float xmin, float dd) {
    uint u0 = pack2_bf16(fmaf((float)(p.x & 3), dd, xmin),
                         fmaf((float)((p.x >> 2) & 3), dd, xmin));
    uint u1 = pack2_bf16(fmaf((float)((p.x >> 4) & 3), dd, xmin),
                         fmaf((float)((p.x >> 6) & 3), dd, xmin));
    uint u2 = pack2_bf16(fmaf((float)(p.y & 3), dd, xmin),
                         fmaf((float)((p.y >> 2) & 3), dd, xmin));
    uint u3 = pack2_bf16(fmaf((float)((p.y >> 4) & 3), dd, xmin),
                         fmaf((float)((p.y >> 6) & 3), dd, xmin));
    uint4 q = make_uint4(u0, u1, u2, u3);
    short8 r;
    __builtin_memcpy(&r, &q, 16);
    return r;
}

// 8 f32 -> short8 bf16
static __device__ __forceinline__ short8 cvt8(float4 a, float4 b) {
    uint4 q = make_uint4(pack2_bf16(a.x, a.y), pack2_bf16(a.z, a.w),
                         pack2_bf16(b.x, b.y), pack2_bf16(b.z, b.w));
    short8 r;
    __builtin_memcpy(&r, &q, 16);
    return r;
}

static __device__ __forceinline__ void gload16(const void* g, void* l) {
    __builtin_amdgcn_global_load_lds((const __attribute__((address_space(1))) void*)g,
                                     (__attribute__((address_space(3))) void*)l,
                                     16, 0, 0);
}

// ---------- kernel 1: persistent fused detect + burst-stage + GEMM ----------
__global__ __launch_bounds__(256, 2)
void gemm_kernel(const float* __restrict__ x,
                 const int* __restrict__ packed,
                 const void* __restrict__ rr,
                 float* __restrict__ part) {
    const int bid  = blockIdx.x;
    const int t    = threadIdx.x;
    const int lane = t & 63;
    const int wv   = t >> 6;

    // W tile: [half][row][512B], 64 KiB. Detection scratch aliases the front
    // (fully consumed + barriered before any staging overwrites it).
    __shared__ __align__(16) char lds[65536];
    int* s_viol = (int*)lds;          // 3 ints
    int* s_max  = (int*)(lds + 16);   // 3 ints
    int* s_fmt  = (int*)(lds + 32);

    // ---- block-local range-dtype detection (verbatim logic, proven) ----
    if (t < 3) { s_viol[t] = 0; s_max[t] = 0; }
    __syncthreads();
    {
        const int g = 1024 + t;   // f32-view reads bytes [8192,10240): in-bounds for all fmts
        const uint   ru = ((const uint*)rr)[g];
        const float2 rf = ((const float2*)rr)[g];
        int viol[3]; float mx[3];
        {   // h0: fp16 pairs
            __half2 h; __builtin_memcpy(&h, &ru, 4);
            const float a = __half2float(h.x), c = __half2float(h.y);
            viol[0] = !(fabsf(a) < 1.f && fabsf(c) < 1.f && a <= c);
            mx[0] = fabsf(c);
        }
        {   // h1: bf16 pairs
            const float a = bf16_to_f((ushort)(ru & 0xffff));
            const float c = bf16_to_f((ushort)(ru >> 16));
            viol[1] = !(fabsf(a) < 1.f && fabsf(c) < 1.f && a <= c);
            mx[1] = fabsf(c);
        }
        {   // h2: f32 pairs
            viol[2] = !(fabsf(rf.x) < 1.f && fabsf(rf.y) < 1.f && rf.x <= rf.y);
            mx[2] = fabsf(rf.y);
        }
#pragma unroll
        for (int h = 0; h < 3; ++h) {
            if (viol[h]) atomicOr(&s_viol[h], 1);
            atomicMax(&s_max[h], __float_as_int(mx[h]));
        }
    }
    __syncthreads();
    if (t == 0) {
        const float lo = 0.02f;
        int f = 0;
        if      (!s_viol[2] && __int_as_float(s_max[2]) > lo) f = 2;
        else if (!s_viol[1] && __int_as_float(s_max[1]) > lo) f = 1;
        *s_fmt = f;
    }
    __syncthreads();
    const int fmt = *s_fmt;
    __syncthreads();   // everyone has fmt in-reg before staging clobbers scratch

    // ---- lane roles ----
    const int r    = lane & 15;          // C col within 16 / A row (acc0)
    const int j    = lane >> 4;          // k-slice (k = j*8 .. +8)
    const int nrow = (wv << 4) | r;      // W row this lane dequants (wave-local!)
    const uint rsw = (uint)((nrow & 7) << 4);
    const int lrow = lane >> 5;          // staging: which of 2 rows per op
    const uint lb  = (uint)((lane & 31) * 16);   // 0..496 within 512-B window
    const int wrow0 = wv * 16;           // wave stages/consumes rows wrow0..+15

    const uint*   rr_u  = (const uint*)rr;
    const float2* rr_f2 = (const float2*)rr;

    for (int tile = bid; tile < NTILES; tile += GRID) {
        const int s  = tile / NB;
        const int nb = tile - s * NB;
        const int n  = nb * BN + nrow;

        // WAR guard: prior tile's ds_reads must retire before DMA re-writes LDS
        asm volatile("s_waitcnt lgkmcnt(0)" ::: "memory");
        __builtin_amdgcn_sched_barrier(0);

        // ---- raw range loads (issued BEFORE staging: oldest in vmcnt queue) ----
        uint4 u0, u1; float4 q0, q1, q2, q3;
        if (fmt == 2) {
            const float4* rp = (const float4*)(rr_f2 + (n * 32 + s * 8));
            q0 = rp[0]; q1 = rp[1]; q2 = rp[2]; q3 = rp[3];
        } else {
            const uint4* up = (const uint4*)(rr_u + (n * 32 + s * 8));
            u0 = up[0]; u1 = up[1];
        }

        // ---- stage W tile: 16 gloads/wave, 512-B contiguous bursts/row ----
        const char* pkb = (const char*)packed + (size_t)(nb * BN) * 4096 + s * 1024;
#pragma unroll
        for (int i = 0; i < 8; ++i) {            // half0: bytes [0,512)
            const int row = wrow0 + 2 * i + lrow;
            const char* g = pkb + (size_t)row * 4096 + (lb ^ (uint)((row & 7) << 4));
            gload16(g, lds + (wrow0 + 2 * i) * 512);
        }
#pragma unroll
        for (int i = 0; i < 8; ++i) {            // half1: bytes [512,1024)
            const int row = wrow0 + 2 * i + lrow;
            const char* g = pkb + (size_t)row * 4096 + 512 + (lb ^ (uint)((row & 7) << 4));
            gload16(g, lds + 32768 + (wrow0 + 2 * i) * 512);
        }

        // ---- decode 8 (xmin, dd) pairs into registers (static after unroll) ----
        float xm[8], dde[8];
        if (fmt == 2) {
            xm[0]=q0.x; dde[0]=(q0.y-q0.x)*(1.f/3.f); xm[1]=q0.z; dde[1]=(q0.w-q0.z)*(1.f/3.f);
            xm[2]=q1.x; dde[2]=(q1.y-q1.x)*(1.f/3.f); xm[3]=q1.z; dde[3]=(q1.w-q1.z)*(1.f/3.f);
            xm[4]=q2.x; dde[4]=(q2.y-q2.x)*(1.f/3.f); xm[5]=q2.z; dde[5]=(q2.w-q2.z)*(1.f/3.f);
            xm[6]=q3.x; dde[6]=(q3.y-q3.x)*(1.f/3.f); xm[7]=q3.z; dde[7]=(q3.w-q3.z)*(1.f/3.f);
        } else {
            uint raw[8] = {u0.x, u0.y, u0.z, u0.w, u1.x, u1.y, u1.z, u1.w};
#pragma unroll
            for (int i = 0; i < 8; ++i) {
                float a, c;
                if (fmt == 1) {
                    a = bf16_to_f((ushort)(raw[i] & 0xffff));
                    c = bf16_to_f((ushort)(raw[i] >> 16));
                } else {
                    __half2 h; __builtin_memcpy(&h, &raw[i], 4);
                    a = __half2float(h.x); c = __half2float(h.y);
                }
                xm[i] = a; dde[i] = (c - a) * (1.f / 3.f);
            }
        }

        // ---- wait half0 only (8 newest = half1 stay in flight); no barrier ----
        asm volatile("s_waitcnt vmcnt(8)" ::: "memory");
        __builtin_amdgcn_sched_barrier(0);

        f32x4 acc0 = {0.f, 0.f, 0.f, 0.f};
        f32x4 acc1 = {0.f, 0.f, 0.f, 0.f};
        const float* xr0 = x + r * IN_F + s * 1024 + j * 8;
        const float* xr1 = xr0 + 16 * IN_F;
        const char*  wp0 = lds + nrow * 512;
        const char*  wp1 = wp0 + 32768;

#pragma unroll
        for (int S = 0; S < 4; ++S) {            // consume half0
#pragma unroll
            for (int kc = 0; kc < 4; ++kc) {
                const int eo = S * 128 + kc * 32;
                float4 xa0 = *(const float4*)(xr0 + eo);
                float4 xb0 = *(const float4*)(xr0 + eo + 4);
                float4 xa1 = *(const float4*)(xr1 + eo);
                float4 xb1 = *(const float4*)(xr1 + eo + 4);
                short8 av0 = cvt8(xa0, xb0);
                short8 av1 = cvt8(xa1, xb1);
                const uint off = ((uint)(S * 128 + kc * 32) | (uint)(j << 3)) ^ rsw;
                const int2 pq = *(const int2*)(wp0 + off);
                const short8 bf = dq8(pq, xm[S], dde[S]);
                acc0 = __builtin_amdgcn_mfma_f32_16x16x32_bf16(av0, bf, acc0, 0, 0, 0);
                acc1 = __builtin_amdgcn_mfma_f32_16x16x32_bf16(av1, bf, acc1, 0, 0, 0);
            }
            __builtin_amdgcn_sched_barrier(0);   // bound cross-step hoisting
        }

        asm volatile("s_waitcnt vmcnt(0)" ::: "memory");   // half1 arrived
        __builtin_amdgcn_sched_barrier(0);

#pragma unroll
        for (int S = 4; S < 8; ++S) {            // consume half1
#pragma unroll
            for (int kc = 0; kc < 4; ++kc) {
                const int eo = S * 128 + kc * 32;
                float4 xa0 = *(const float4*)(xr0 + eo);
                float4 xb0 = *(const float4*)(xr0 + eo + 4);
                float4 xa1 = *(const float4*)(xr1 + eo);
                float4 xb1 = *(const float4*)(xr1 + eo + 4);
                short8 av0 = cvt8(xa0, xb0);
                short8 av1 = cvt8(xa1, xb1);
                const uint off = ((uint)((S - 4) * 128 + kc * 32) | (uint)(j << 3)) ^ rsw;
                const int2 pq = *(const int2*)(wp1 + off);
                const short8 bf = dq8(pq, xm[S], dde[S]);
                acc0 = __builtin_amdgcn_mfma_f32_16x16x32_bf16(av0, bf, acc0, 0, 0, 0);
                acc1 = __builtin_amdgcn_mfma_f32_16x16x32_bf16(av1, bf, acc1, 0, 0, 0);
            }
            __builtin_amdgcn_sched_barrier(0);
        }

        // ---- epilogue: split-K partial stores ----
        // C/D layout col=lane&15, row=(lane>>4)*4+reg (m89-verified)
        float* pout = part + (size_t)s * (32 * OUT_F);
        const int r0 = j << 2;
#pragma unroll
        for (int v = 0; v < 4; ++v) {
            pout[(r0 + v) * OUT_F + n]      = acc0[v];
            pout[(16 + r0 + v) * OUT_F + n] = acc1[v];
        }
    }
}

// ---------- kernel 2: out = bias + sum of split-K partials ----------
__global__ __launch_bounds__(256)
void reduce_kernel(const float* __restrict__ part,
                   const float* __restrict__ bias,
                   float* __restrict__ out) {
    const int i = blockIdx.x * 256 + threadIdx.x;   // 0..88063 float4 units
    const int n4 = i % 2752;                        // 11008/4
    const float4* p4 = (const float4*)part;
    float4 a = ((const float4*)bias)[n4];
#pragma unroll
    for (int ss = 0; ss < SPLITS; ++ss) {
        const float4 v = p4[ss * 88064 + i];
        a.x += v.x; a.y += v.y; a.z += v.z; a.w += v.w;
    }
    ((float4*)out)[i] = a;
}

extern "C" void kernel_launch(void* const* d_in, const int* in_sizes, int n_in,
                              void* d_out, int out_size, void* d_ws, size_t ws_size,
                              hipStream_t stream) {
    const float* x      = (const float*)d_in[0];
    const int*   packed = (const int*)d_in[1];
    const void*  rr     = (const void*)d_in[2];
    const float* bias   = (const float*)d_in[3];
    float*       out    = (float*)d_out;
    float*       part   = (float*)d_ws;   // 4*32*11008 f32 = 5.6 MB

    gemm_kernel<<<GRID, 256, 0, stream>>>(x, packed, rr, part);
    reduce_kernel<<<344, 256, 0, stream>>>(part, bias, out);
}

// Round 12
// 53.801 us; speedup vs baseline: 1.9374x; 1.1874x over previous
//
#include <hip/hip_runtime.h>
#include <hip/hip_bf16.h>
#include <hip/hip_fp16.h>

typedef __attribute__((ext_vector_type(8))) short short8;   // 8 x bf16 (4 VGPRs)
typedef __attribute__((ext_vector_type(4))) float f32x4;    // MFMA accumulator

#define OUT_F  11008
#define IN_F   4096
#define BN     64
#define SPLITS 8                       // 512-elem K-span per split
#define NB     (OUT_F / BN)            // 172
#define NGRP   (OUT_F * IN_F / 128)    // 352256 quant groups

// workspace layout (bytes)
#define WS_RNG  0                        // float2 {xmin, dd}, TRANSPOSED [kb][n]: 2818048 B
#define WS_XB   (NGRP * 8)               // bf16 x: 32*4096*2 = 262144 B
#define WS_PART (WS_XB + 32 * IN_F * 2)  // split-K partials: 8*32*11008*4 B = 11.3 MB

// ---------- helpers ----------
static __device__ __forceinline__ uint pack2_bf16(float a, float b) {
    __hip_bfloat162 h = __float22bfloat162_rn(make_float2(a, b));
    uint u;
    __builtin_memcpy(&u, &h, 4);
    return u;
}

static __device__ __forceinline__ float bf16_to_f(ushort u) {
    return __uint_as_float(((uint)u) << 16);
}

// dequant 8 weights (2 packed ints, low bytes) -> short8 bf16  [proven R5-R11]
static __device__ __forceinline__ short8 dq8(int2 p, float xmin, float dd) {
    uint u0 = pack2_bf16(fmaf((float)(p.x & 3), dd, xmin),
                         fmaf((float)((p.x >> 2) & 3), dd, xmin));
    uint u1 = pack2_bf16(fmaf((float)((p.x >> 4) & 3), dd, xmin),
                         fmaf((float)((p.x >> 6) & 3), dd, xmin));
    uint u2 = pack2_bf16(fmaf((float)(p.y & 3), dd, xmin),
                         fmaf((float)((p.y >> 2) & 3), dd, xmin));
    uint u3 = pack2_bf16(fmaf((float)((p.y >> 4) & 3), dd, xmin),
                         fmaf((float)((p.y >> 6) & 3), dd, xmin));
    uint4 q = make_uint4(u0, u1, u2, u3);
    short8 r;
    __builtin_memcpy(&r, &q, 16);
    return r;
}

// ---------- kernel 1: x->bf16 | detect dtype + decode ranges (transposed) ----------
// [verbatim from R6/R7 -- end-to-end validated]
__global__ __launch_bounds__(256)
void prep_kernel(const float* __restrict__ x,
                 const void* __restrict__ rr,
                 char* __restrict__ ws) {
    const int b = blockIdx.x;
    const int t = threadIdx.x;
    if (b < 128) {
        const int i = b * 256 + t;
        const float4 v = ((const float4*)x)[i];
        ushort4 o;
        __hip_bfloat16 h0 = __float2bfloat16(v.x);
        __hip_bfloat16 h1 = __float2bfloat16(v.y);
        __hip_bfloat16 h2 = __float2bfloat16(v.z);
        __hip_bfloat16 h3 = __float2bfloat16(v.w);
        __builtin_memcpy(&o.x, &h0, 2);
        __builtin_memcpy(&o.y, &h1, 2);
        __builtin_memcpy(&o.z, &h2, 2);
        __builtin_memcpy(&o.w, &h3, 2);
        ((ushort4*)(ws + WS_XB))[i] = o;
        return;
    }
    __shared__ int s_viol[3];
    __shared__ int s_max[3];
    __shared__ int s_fmt;
    if (t < 3) { s_viol[t] = 0; s_max[t] = 0; }
    __syncthreads();
    {
        const int g = 1024 + t;   // f32-view reads bytes [8192,10240): in-bounds for all fmts
        const uint   ru = ((const uint*)rr)[g];
        const float2 rf = ((const float2*)rr)[g];
        int viol[3]; float mx[3];
        {   // h0: fp16 pairs
            __half2 h; __builtin_memcpy(&h, &ru, 4);
            const float a = __half2float(h.x), c = __half2float(h.y);
            viol[0] = !(fabsf(a) < 1.f && fabsf(c) < 1.f && a <= c);
            mx[0] = fabsf(c);
        }
        {   // h1: bf16 pairs
            const float a = bf16_to_f((ushort)(ru & 0xffff));
            const float c = bf16_to_f((ushort)(ru >> 16));
            viol[1] = !(fabsf(a) < 1.f && fabsf(c) < 1.f && a <= c);
            mx[1] = fabsf(c);
        }
        {   // h2: f32 pairs
            viol[2] = !(fabsf(rf.x) < 1.f && fabsf(rf.y) < 1.f && rf.x <= rf.y);
            mx[2] = fabsf(rf.y);
        }
#pragma unroll
        for (int h = 0; h < 3; ++h) {
            if (viol[h]) atomicOr(&s_viol[h], 1);
            atomicMax(&s_max[h], __float_as_int(mx[h]));
        }
    }
    __syncthreads();
    if (t == 0) {
        const float lo = 0.02f;
        int f = 0;
        if      (!s_viol[2] && __int_as_float(s_max[2]) > lo) f = 2;
        else if (!s_viol[1] && __int_as_float(s_max[1]) > lo) f = 1;
        s_fmt = f;
    }
    __syncthreads();
    const int fmt = s_fmt;

    // decode this block's 32 rows x 32 kb -> TRANSPOSED rngT[kb][n]
    const int n0 = (b - 128) * 32;          // 344 blocks * 32 rows = 11008 rows
    const int nl = t & 31;
    const int kbg = t >> 5;
    float2* rngT = (float2*)(ws + WS_RNG);
#pragma unroll
    for (int jj = 0; jj < 4; ++jj) {
        const int kb = kbg * 4 + jj;
        const int g  = (n0 + nl) * 32 + kb;
        float xmin, xmax;
        if (fmt == 2) {
            const float2 f = ((const float2*)rr)[g];
            xmin = f.x; xmax = f.y;
        } else if (fmt == 1) {
            const uint u = ((const uint*)rr)[g];
            xmin = bf16_to_f((ushort)(u & 0xffff));
            xmax = bf16_to_f((ushort)(u >> 16));
        } else {
            uint u = ((const uint*)rr)[g];
            __half2 h; __builtin_memcpy(&h, &u, 4);
            xmin = __half2float(h.x); xmax = __half2float(h.y);
        }
        rngT[kb * OUT_F + n0 + nl] = make_float2(xmin, (xmax - xmin) * (1.0f / 3.0f));
    }
}

// ---------- kernel 2: register-direct GEMM. No LDS, no barriers, no waits ----------
// Pure latency-flood: ~12 independent VMEM in flight per lane (unroll 4),
// ~5 blocks/CU (SPLITS=8 -> 1376 blocks). All operands consumed in-register.
__global__ __launch_bounds__(256, 4)
void gemm_kernel(const int* __restrict__ packed,
                 const char* __restrict__ ws,
                 float* __restrict__ part) {
    const int nb   = blockIdx.x;   // 0..171 (64 output cols)
    const int s    = blockIdx.y;   // 0..7   (K split: 512 elems each)
    const int t    = threadIdx.x;
    const int lane = t & 63;
    const int wv   = t >> 6;

    const float2* rngT = (const float2*)(ws + WS_RNG);
    const ushort* xb   = (const ushort*)(ws + WS_XB);

    const int r    = lane & 15;        // C col within 16 / A row (acc0)
    const int j    = lane >> 4;        // k-slice (k = j*8 .. +8)
    const int nrow = (wv << 4) | r;    // W row this lane dequants
    const int n    = nb * BN + nrow;

    // W: row n bytes [s*512, +512); step t uses int2 at +t*32 + j*8.
    // Wave footprint per step: 16 rows x 32 B contiguous; consecutive steps
    // finish each 128-B line back-to-back (L1-resident).
    const char* wp = (const char*)packed + (size_t)n * 4096 + s * 512 + (j << 3);
    // A: bf16 x rows r / r+16, k base s*512 + j*8
    const ushort* xa0 = xb + r * IN_F + s * 512 + (j << 3);
    const ushort* xa1 = xa0 + 16 * IN_F;
    // ranges: transposed [kb][n]; wave's 16 rows = 64 B contiguous (L1-broadcast)
    const float2* rb = rngT + (size_t)(s * 4) * OUT_F + n;

    f32x4 acc0 = {0.f, 0.f, 0.f, 0.f};
    f32x4 acc1 = {0.f, 0.f, 0.f, 0.f};

#pragma unroll 4
    for (int st = 0; st < 16; ++st) {
        const float2 rc = rb[(size_t)(st >> 2) * OUT_F];
        const int2   pq = *(const int2*)(wp + st * 32);
        const short8 a0 = *(const short8*)(xa0 + st * 32);
        const short8 a1 = *(const short8*)(xa1 + st * 32);
        const short8 bf = dq8(pq, rc.x, rc.y);
        acc0 = __builtin_amdgcn_mfma_f32_16x16x32_bf16(a0, bf, acc0, 0, 0, 0);
        acc1 = __builtin_amdgcn_mfma_f32_16x16x32_bf16(a1, bf, acc1, 0, 0, 0);
    }

    // ---- epilogue: split-K partial stores ----
    // C/D layout col=lane&15, row=(lane>>4)*4+reg (m89-verified)
    float* pout = part + (size_t)s * (32 * OUT_F);
    const int r0 = j << 2;
#pragma unroll
    for (int v = 0; v < 4; ++v) {
        pout[(r0 + v) * OUT_F + n]      = acc0[v];
        pout[(16 + r0 + v) * OUT_F + n] = acc1[v];
    }
}

// ---------- kernel 3: out = bias + sum of split-K partials ----------
__global__ __launch_bounds__(256)
void reduce_kernel(const float* __restrict__ part,
                   const float* __restrict__ bias,
                   float* __restrict__ out) {
    const int i = blockIdx.x * 256 + threadIdx.x;   // 0..88063 float4 units
    const int n4 = i % 2752;                        // 11008/4
    const float4* p4 = (const float4*)part;
    float4 a = ((const float4*)bias)[n4];
#pragma unroll
    for (int ss = 0; ss < SPLITS; ++ss) {
        const float4 v = p4[ss * 88064 + i];
        a.x += v.x; a.y += v.y; a.z += v.z; a.w += v.w;
    }
    ((float4*)out)[i] = a;
}

extern "C" void kernel_launch(void* const* d_in, const int* in_sizes, int n_in,
                              void* d_out, int out_size, void* d_ws, size_t ws_size,
                              hipStream_t stream) {
    const float* x      = (const float*)d_in[0];
    const int*   packed = (const int*)d_in[1];
    const void*  rr     = (const void*)d_in[2];
    const float* bias   = (const float*)d_in[3];
    float*       out    = (float*)d_out;
    char*        ws     = (char*)d_ws;
    float*       part   = (float*)(ws + WS_PART);

    prep_kernel<<<472, 256, 0, stream>>>(x, rr, ws);
    gemm_kernel<<<dim3(NB, SPLITS), 256, 0, stream>>>(packed, ws, part);
    reduce_kernel<<<344, 256, 0, stream>>>(part, bias, out);
}

// Round 13
// 53.229 us; speedup vs baseline: 1.9583x; 1.0108x over previous
//
#include <hip/hip_runtime.h>
#include <hip/hip_bf16.h>
#include <hip/hip_fp16.h>

typedef __attribute__((ext_vector_type(8))) short short8;   // 8 x bf16 (4 VGPRs)
typedef __attribute__((ext_vector_type(4))) float f32x4;    // MFMA accumulator

#define OUT_F  11008
#define IN_F   4096
#define BN     64
#define SPLITS 16                      // 256-elem K-span per split
#define NB     (OUT_F / BN)            // 172
#define NGRP   (OUT_F * IN_F / 128)    // 352256 quant groups

// workspace layout (bytes)
#define WS_RNG  0                        // float2 {xmin, dd}, TRANSPOSED [kb][n]: 2818048 B
#define WS_XB   (NGRP * 8)               // bf16 x: 32*4096*2 = 262144 B
#define WS_PART (WS_XB + 32 * IN_F * 2)  // split-K partials: 16*32*11008*4 B = 22.5 MB

// ---------- helpers ----------
static __device__ __forceinline__ uint pack2_bf16(float a, float b) {
    __hip_bfloat162 h = __float22bfloat162_rn(make_float2(a, b));
    uint u;
    __builtin_memcpy(&u, &h, 4);
    return u;
}

static __device__ __forceinline__ float bf16_to_f(ushort u) {
    return __uint_as_float(((uint)u) << 16);
}

// dequant 8 weights (2 packed ints, low bytes) -> short8 bf16  [proven R5-R12]
static __device__ __forceinline__ short8 dq8(int2 p, float xmin, float dd) {
    uint u0 = pack2_bf16(fmaf((float)(p.x & 3), dd, xmin),
                         fmaf((float)((p.x >> 2) & 3), dd, xmin));
    uint u1 = pack2_bf16(fmaf((float)((p.x >> 4) & 3), dd, xmin),
                         fmaf((float)((p.x >> 6) & 3), dd, xmin));
    uint u2 = pack2_bf16(fmaf((float)(p.y & 3), dd, xmin),
                         fmaf((float)((p.y >> 2) & 3), dd, xmin));
    uint u3 = pack2_bf16(fmaf((float)((p.y >> 4) & 3), dd, xmin),
                         fmaf((float)((p.y >> 6) & 3), dd, xmin));
    uint4 q = make_uint4(u0, u1, u2, u3);
    short8 r;
    __builtin_memcpy(&r, &q, 16);
    return r;
}

// ---------- kernel 1: x->bf16 | detect dtype + decode ranges (transposed) ----------
// [verbatim from R6/R7/R12 -- end-to-end validated]
__global__ __launch_bounds__(256)
void prep_kernel(const float* __restrict__ x,
                 const void* __restrict__ rr,
                 char* __restrict__ ws) {
    const int b = blockIdx.x;
    const int t = threadIdx.x;
    if (b < 128) {
        const int i = b * 256 + t;
        const float4 v = ((const float4*)x)[i];
        ushort4 o;
        __hip_bfloat16 h0 = __float2bfloat16(v.x);
        __hip_bfloat16 h1 = __float2bfloat16(v.y);
        __hip_bfloat16 h2 = __float2bfloat16(v.z);
        __hip_bfloat16 h3 = __float2bfloat16(v.w);
        __builtin_memcpy(&o.x, &h0, 2);
        __builtin_memcpy(&o.y, &h1, 2);
        __builtin_memcpy(&o.z, &h2, 2);
        __builtin_memcpy(&o.w, &h3, 2);
        ((ushort4*)(ws + WS_XB))[i] = o;
        return;
    }
    __shared__ int s_viol[3];
    __shared__ int s_max[3];
    __shared__ int s_fmt;
    if (t < 3) { s_viol[t] = 0; s_max[t] = 0; }
    __syncthreads();
    {
        const int g = 1024 + t;   // f32-view reads bytes [8192,10240): in-bounds for all fmts
        const uint   ru = ((const uint*)rr)[g];
        const float2 rf = ((const float2*)rr)[g];
        int viol[3]; float mx[3];
        {   // h0: fp16 pairs
            __half2 h; __builtin_memcpy(&h, &ru, 4);
            const float a = __half2float(h.x), c = __half2float(h.y);
            viol[0] = !(fabsf(a) < 1.f && fabsf(c) < 1.f && a <= c);
            mx[0] = fabsf(c);
        }
        {   // h1: bf16 pairs
            const float a = bf16_to_f((ushort)(ru & 0xffff));
            const float c = bf16_to_f((ushort)(ru >> 16));
            viol[1] = !(fabsf(a) < 1.f && fabsf(c) < 1.f && a <= c);
            mx[1] = fabsf(c);
        }
        {   // h2: f32 pairs
            viol[2] = !(fabsf(rf.x) < 1.f && fabsf(rf.y) < 1.f && rf.x <= rf.y);
            mx[2] = fabsf(rf.y);
        }
#pragma unroll
        for (int h = 0; h < 3; ++h) {
            if (viol[h]) atomicOr(&s_viol[h], 1);
            atomicMax(&s_max[h], __float_as_int(mx[h]));
        }
    }
    __syncthreads();
    if (t == 0) {
        const float lo = 0.02f;
        int f = 0;
        if      (!s_viol[2] && __int_as_float(s_max[2]) > lo) f = 2;
        else if (!s_viol[1] && __int_as_float(s_max[1]) > lo) f = 1;
        s_fmt = f;
    }
    __syncthreads();
    const int fmt = s_fmt;

    // decode this block's 32 rows x 32 kb -> TRANSPOSED rngT[kb][n]
    const int n0 = (b - 128) * 32;          // 344 blocks * 32 rows = 11008 rows
    const int nl = t & 31;
    const int kbg = t >> 5;
    float2* rngT = (float2*)(ws + WS_RNG);
#pragma unroll
    for (int jj = 0; jj < 4; ++jj) {
        const int kb = kbg * 4 + jj;
        const int g  = (n0 + nl) * 32 + kb;
        float xmin, xmax;
        if (fmt == 2) {
            const float2 f = ((const float2*)rr)[g];
            xmin = f.x; xmax = f.y;
        } else if (fmt == 1) {
            const uint u = ((const uint*)rr)[g];
            xmin = bf16_to_f((ushort)(u & 0xffff));
            xmax = bf16_to_f((ushort)(u >> 16));
        } else {
            uint u = ((const uint*)rr)[g];
            __half2 h; __builtin_memcpy(&h, &u, 4);
            xmin = __half2float(h.x); xmax = __half2float(h.y);
        }
        rngT[kb * OUT_F + n0 + nl] = make_float2(xmin, (xmax - xmin) * (1.0f / 3.0f));
    }
}

// ---------- kernel 2: register-direct GEMM with FORCED upfront loads ----------
// Phase 1 loads ALL W-operands for the block's K-span into registers;
// sched_barrier(0) pins them before Phase 2 consumes. 4 KB in flight/wave.
__global__ __launch_bounds__(256, 4)
void gemm_kernel(const int* __restrict__ packed,
                 const char* __restrict__ ws,
                 float* __restrict__ part) {
    const int nb   = blockIdx.x;   // 0..171 (64 output cols)
    const int s    = blockIdx.y;   // 0..15  (K split: 256 elems each)
    const int t    = threadIdx.x;
    const int lane = t & 63;
    const int wv   = t >> 6;

    const float2* rngT = (const float2*)(ws + WS_RNG);
    const ushort* xb   = (const ushort*)(ws + WS_XB);

    const int r    = lane & 15;        // C col within 16 / A row (acc0)
    const int j    = lane >> 4;        // k-slice (k = j*8 .. +8)
    const int nrow = (wv << 4) | r;    // W row this lane dequants
    const int n    = nb * BN + nrow;

    // W: row n bytes [s*256, +256); step st uses int2 at +st*32 + j*8.
    const char* wp = (const char*)packed + (size_t)n * 4096 + s * 256 + (j << 3);
    // A: bf16 x rows r / r+16, k base s*256 + j*8
    const ushort* xa0 = xb + r * IN_F + s * 256 + (j << 3);
    const ushort* xa1 = xa0 + 16 * IN_F;
    // ranges: transposed [kb][n]; kb = 2s + (st>>2)
    const float2* rb = rngT + (size_t)(s * 2) * OUT_F + n;

    // ---- Phase 1: issue ALL independent loads ----
    int2 pq[8];
#pragma unroll
    for (int st = 0; st < 8; ++st)
        pq[st] = *(const int2*)(wp + st * 32);
    float2 rc0 = rb[0];
    float2 rc1 = rb[OUT_F];

    __builtin_amdgcn_sched_barrier(0);   // nothing moves across: all 10 loads in flight

    // ---- Phase 2: consume ----
    f32x4 acc0 = {0.f, 0.f, 0.f, 0.f};
    f32x4 acc1 = {0.f, 0.f, 0.f, 0.f};
#pragma unroll
    for (int st = 0; st < 8; ++st) {
        const short8 a0 = *(const short8*)(xa0 + st * 32);
        const short8 a1 = *(const short8*)(xa1 + st * 32);
        const float2 rc = (st < 4) ? rc0 : rc1;
        const short8 bf = dq8(pq[st], rc.x, rc.y);
        acc0 = __builtin_amdgcn_mfma_f32_16x16x32_bf16(a0, bf, acc0, 0, 0, 0);
        acc1 = __builtin_amdgcn_mfma_f32_16x16x32_bf16(a1, bf, acc1, 0, 0, 0);
    }

    // ---- epilogue: split-K partial stores ----
    // C/D layout col=lane&15, row=(lane>>4)*4+reg (m89-verified)
    float* pout = part + (size_t)s * (32 * OUT_F);
    const int r0 = j << 2;
#pragma unroll
    for (int v = 0; v < 4; ++v) {
        pout[(r0 + v) * OUT_F + n]      = acc0[v];
        pout[(16 + r0 + v) * OUT_F + n] = acc1[v];
    }
}

// ---------- kernel 3: out = bias + sum of split-K partials ----------
__global__ __launch_bounds__(256)
void reduce_kernel(const float* __restrict__ part,
                   const float* __restrict__ bias,
                   float* __restrict__ out) {
    const int i = blockIdx.x * 256 + threadIdx.x;   // 0..88063 float4 units
    const int n4 = i % 2752;                        // 11008/4
    const float4* p4 = (const float4*)part;
    float4 a = ((const float4*)bias)[n4];
#pragma unroll
    for (int ss = 0; ss < SPLITS; ++ss) {
        const float4 v = p4[ss * 88064 + i];
        a.x += v.x; a.y += v.y; a.z += v.z; a.w += v.w;
    }
    ((float4*)out)[i] = a;
}

extern "C" void kernel_launch(void* const* d_in, const int* in_sizes, int n_in,
                              void* d_out, int out_size, void* d_ws, size_t ws_size,
                              hipStream_t stream) {
    const float* x      = (const float*)d_in[0];
    const int*   packed = (const int*)d_in[1];
    const void*  rr     = (const void*)d_in[2];
    const float* bias   = (const float*)d_in[3];
    float*       out    = (float*)d_out;
    char*        ws     = (char*)d_ws;
    float*       part   = (float*)(ws + WS_PART);

    prep_kernel<<<472, 256, 0, stream>>>(x, rr, ws);
    gemm_kernel<<<dim3(NB, SPLITS), 256, 0, stream>>>(packed, ws, part);
    reduce_kernel<<<344, 256, 0, stream>>>(part, bias, out);
}